// Round 7
// baseline (779.199 us; speedup 1.0000x reference)
//
#include <hip/hip_runtime.h>
#include <math.h>

#define BATCH 16
#define CIN   512
#define MID   256
#define HW    4096
#define HEADS 8
#define CH    32
#define KSPL  8
#define PI2   6.2831853071795864769f
#define RT2H  0.70710678118654752440f

typedef __attribute__((ext_vector_type(8))) short short8;
typedef __attribute__((ext_vector_type(4))) float floatx4;
typedef __attribute__((ext_vector_type(16))) float floatx16;

__device__ inline unsigned short f2b(float f) {
  union { float f; unsigned int u; } v; v.f = f;
  unsigned int u = v.u;
  unsigned int r = (u + 0x7fffu + ((u >> 16) & 1u)) >> 16;
  return (unsigned short)r;
}

// ------------------------------------------------------------------ DFT helpers
__device__ __forceinline__ int swidx(int r, int n) {
  return (r << 6) + (n ^ (r & 15));
}

__device__ __forceinline__ void cmadd(float2& a, const float2 x,
                                      const float wr, const float wi) {
  a.x = fmaf(x.x, wr, a.x); a.x = fmaf(-x.y, wi, a.x);
  a.y = fmaf(x.x, wi, a.y); a.y = fmaf(x.y, wr, a.y);
}

// In-place 64-point DFT along axis; Cooley-Tukey 8x8 (see prior rounds).
template<int SGN, int AXIS>
__device__ __forceinline__ void dft64_pass(float2* __restrict__ buf,
                                           const float2* __restrict__ tw,
                                           const int tid)
{
  constexpr float W8R[8] = {1.f, RT2H, 0.f, -RT2H, -1.f, -RT2H, 0.f, RT2H};
  constexpr float W8I[8] = {0.f, RT2H, 1.f, RT2H, 0.f, -RT2H, -1.f, -RT2H};
  const int line = tid & 63;
  const int wv = tid >> 6;
  float2 xa[2][8];

  #pragma unroll
  for (int t = 0; t < 2; ++t) {
    const int b = wv + (t << 2);
    #pragma unroll
    for (int a = 0; a < 8; ++a) {
      const int i = (a << 3) + b;
      xa[t][a] = buf[AXIS ? swidx(line, i) : swidx(i, line)];
    }
  }
  __syncthreads();
  #pragma unroll
  for (int t = 0; t < 2; ++t) {
    const int b = wv + (t << 2);
    #pragma unroll
    for (int d = 0; d < 8; ++d) {
      float2 y = make_float2(0.f, 0.f);
      #pragma unroll
      for (int a = 0; a < 8; ++a) {
        const int j = (a * d) & 7;
        cmadd(y, xa[t][a], W8R[j], (float)SGN * W8I[j]);
      }
      const float2 tb = tw[(b * d) & 63];
      float2 z;
      z.x = y.x * tb.x - y.y * tb.y;
      z.y = y.x * tb.y + y.y * tb.x;
      const int i = (b << 3) + d;
      buf[AXIS ? swidx(line, i) : swidx(i, line)] = z;
    }
  }
  __syncthreads();

  #pragma unroll
  for (int t = 0; t < 2; ++t) {
    const int d = wv + (t << 2);
    #pragma unroll
    for (int b = 0; b < 8; ++b) {
      const int i = (b << 3) + d;
      xa[t][b] = buf[AXIS ? swidx(line, i) : swidx(i, line)];
    }
  }
  __syncthreads();
  #pragma unroll
  for (int t = 0; t < 2; ++t) {
    const int d = wv + (t << 2);
    #pragma unroll
    for (int c = 0; c < 8; ++c) {
      float2 s = make_float2(0.f, 0.f);
      #pragma unroll
      for (int b = 0; b < 8; ++b) {
        const int j = (b * c) & 7;
        cmadd(s, xa[t][b], W8R[j], (float)SGN * W8I[j]);
      }
      const int i = (c << 3) + d;
      buf[AXIS ? swidx(line, i) : swidx(i, line)] = s;
    }
  }
  __syncthreads();
}

// ------------------------------------------------------------------ K0: cast weights to bf16
__global__ __launch_bounds__(256) void k_castw(
    const float* __restrict__ rw, const float* __restrict__ pw,
    unsigned short* __restrict__ rwB, unsigned short* __restrict__ pwB)
{
  int i = blockIdx.x * 256 + threadIdx.x;
  if (i < MID * CIN) rwB[i] = f2b(rw[i]);
  if (i < CIN * 2 * MID) pwB[i] = f2b(pw[i]);
}

// ------------------------------------------------------------------ MFMA GEMM: C[M x N] = A[M x K bf16] * B[K x N] (+bias)(+resid)
// tile 128x128, BK=64, 4 waves, 4x4 mfma_f32_16x16x32_bf16 per wave.
// A-frags read DIRECTLY from global (L2-resident weights, aligned dwordx4).
// B staged via 8x2 register transpose -> ds_write_b128, 16B-block XOR swizzle
// q' = q ^ ((n>>1)&7) on write AND read. Double-buffered Bs + register
// prefetch of step t+1 issued before step t's MFMAs; ONE barrier per K-step.

// variant 1: B = fp32 global (x), converted during staging
__global__ __launch_bounds__(256) void k_gemm_red(
    const unsigned short* __restrict__ A, const float* __restrict__ Bg0,
    const float* __restrict__ bias, float* __restrict__ out)
{
  __shared__ __align__(16) char Bs[2][128 * 144];
  const int tid = threadIdx.x;
  const int n0 = blockIdx.x << 7;
  const int m0 = blockIdx.y << 7;
  const int b  = blockIdx.z;
  const int lane = tid & 63, wave = tid >> 6;
  const int wm = (wave >> 1) << 6, wn = (wave & 1) << 6;
  const int l16 = lane & 15, quad = lane >> 4;
  const int np = tid & 63;          // n-pair
  const int qw = tid >> 6;          // k-quad base; q = qw + 4*it
  const float* Bg = Bg0 + (size_t)b * CIN * HW;
  floatx4 acc[4][4] = {};
  float2 pva[2][4], pvb[2][4];

  // prologue: load + stage step 0
  #pragma unroll
  for (int it = 0; it < 2; ++it) {
    int q = qw + (it << 2);
    const float* r0 = Bg + (size_t)(q << 3) * HW + n0 + (np << 1);
    #pragma unroll
    for (int p = 0; p < 4; ++p) {
      pva[it][p] = *(const float2*)(r0 + (size_t)(2 * p) * HW);
      pvb[it][p] = *(const float2*)(r0 + (size_t)(2 * p + 1) * HW);
    }
  }
  #pragma unroll
  for (int it = 0; it < 2; ++it) {
    int q = qw + (it << 2);
    unsigned int d0[4], d1[4];
    #pragma unroll
    for (int p = 0; p < 4; ++p) {
      d0[p] = (unsigned)f2b(pva[it][p].x) | ((unsigned)f2b(pvb[it][p].x) << 16);
      d1[p] = (unsigned)f2b(pva[it][p].y) | ((unsigned)f2b(pvb[it][p].y) << 16);
    }
    char* dst = Bs[0] + (np << 1) * 144 + ((q ^ (np & 7)) << 4);
    *(uint4*)dst = make_uint4(d0[0], d0[1], d0[2], d0[3]);
    *(uint4*)(dst + 144) = make_uint4(d1[0], d1[1], d1[2], d1[3]);
  }
  int cur = 0;
  for (int t = 0; t < 8; ++t) {
    const int k0 = t << 6;
    __syncthreads();
    if (t < 7) {  // issue global loads for step t+1 (in flight across MFMAs)
      #pragma unroll
      for (int it = 0; it < 2; ++it) {
        int q = qw + (it << 2);
        const float* r0 = Bg + (size_t)(k0 + 64 + (q << 3)) * HW + n0 + (np << 1);
        #pragma unroll
        for (int p = 0; p < 4; ++p) {
          pva[it][p] = *(const float2*)(r0 + (size_t)(2 * p) * HW);
          pvb[it][p] = *(const float2*)(r0 + (size_t)(2 * p + 1) * HW);
        }
      }
    }
    #pragma unroll
    for (int kk = 0; kk < 2; ++kk) {
      short8 af[4], bf[4];
      #pragma unroll
      for (int mi = 0; mi < 4; ++mi)
        af[mi] = *(const short8*)&A[(size_t)(m0 + wm + (mi << 4) + l16) * CIN
                                    + k0 + (kk << 5) + (quad << 3)];
      #pragma unroll
      for (int ni = 0; ni < 4; ++ni) {
        int n = wn + (ni << 4) + l16;
        bf[ni] = *(const short8*)(Bs[cur] + n * 144 + ((((kk << 2) + quad) ^ ((n >> 1) & 7)) << 4));
      }
      #pragma unroll
      for (int mi = 0; mi < 4; ++mi)
        #pragma unroll
        for (int ni = 0; ni < 4; ++ni)
          acc[mi][ni] = __builtin_amdgcn_mfma_f32_16x16x32_bf16(af[mi], bf[ni], acc[mi][ni], 0, 0, 0);
    }
    if (t < 7) {  // pack + write into the other buffer (no barrier needed here)
      #pragma unroll
      for (int it = 0; it < 2; ++it) {
        int q = qw + (it << 2);
        unsigned int d0[4], d1[4];
        #pragma unroll
        for (int p = 0; p < 4; ++p) {
          d0[p] = (unsigned)f2b(pva[it][p].x) | ((unsigned)f2b(pvb[it][p].x) << 16);
          d1[p] = (unsigned)f2b(pva[it][p].y) | ((unsigned)f2b(pvb[it][p].y) << 16);
        }
        char* dst = Bs[cur ^ 1] + (np << 1) * 144 + ((q ^ (np & 7)) << 4);
        *(uint4*)dst = make_uint4(d0[0], d0[1], d0[2], d0[3]);
        *(uint4*)(dst + 144) = make_uint4(d1[0], d1[1], d1[2], d1[3]);
      }
    }
    cur ^= 1;
  }
  #pragma unroll
  for (int mi = 0; mi < 4; ++mi)
    #pragma unroll
    for (int reg = 0; reg < 4; ++reg) {
      int m = m0 + wm + (mi << 4) + (quad << 2) + reg;
      float bv = bias[m];
      size_t base = ((size_t)b * MID + m) * HW + n0 + wn + l16;
      #pragma unroll
      for (int ni = 0; ni < 4; ++ni)
        out[base + (ni << 4)] = acc[mi][ni][reg] + bv;
    }
}

// variant 2: B = bf16 rows scattered in fftf planes; +bias +residual
__global__ __launch_bounds__(256) void k_gemm_post(
    const unsigned short* __restrict__ A, const float* __restrict__ fftf,
    const float* __restrict__ bias, const float* __restrict__ x,
    float* __restrict__ y)
{
  __shared__ __align__(16) char Bs[2][128 * 144];
  const int tid = threadIdx.x;
  const int n0 = blockIdx.x << 7;
  const int m0 = blockIdx.y << 7;
  const int b  = blockIdx.z;
  const int lane = tid & 63, wave = tid >> 6;
  const int wm = (wave >> 1) << 6, wn = (wave & 1) << 6;
  const int l16 = lane & 15, quad = lane >> 4;
  const int np = tid & 63;
  const int qw = tid >> 6;
  floatx4 acc[4][4] = {};
  unsigned int ua[2][4], ub[2][4];

  // prologue: load + stage step 0
  #pragma unroll
  for (int it = 0; it < 2; ++it) {
    int q = qw + (it << 2);
    int c0 = q << 3;                 // 8 channels, never straddles MID
    const unsigned short* bp = (const unsigned short*)
        (fftf + (size_t)(b * MID + (c0 & 255)) * (2 * HW) + ((c0 < MID) ? HW : 0));
    const unsigned int* bp32 = (const unsigned int*)(bp + n0) + np;
    #pragma unroll
    for (int p = 0; p < 4; ++p) {
      ua[it][p] = bp32[(size_t)(2 * p) * (2 * HW)];
      ub[it][p] = bp32[(size_t)(2 * p + 1) * (2 * HW)];
    }
  }
  #pragma unroll
  for (int it = 0; it < 2; ++it) {
    int q = qw + (it << 2);
    unsigned int d0[4], d1[4];
    #pragma unroll
    for (int p = 0; p < 4; ++p) {
      d0[p] = (ua[it][p] & 0xffffu) | (ub[it][p] << 16);
      d1[p] = (ua[it][p] >> 16) | (ub[it][p] & 0xffff0000u);
    }
    char* dst = Bs[0] + (np << 1) * 144 + ((q ^ (np & 7)) << 4);
    *(uint4*)dst = make_uint4(d0[0], d0[1], d0[2], d0[3]);
    *(uint4*)(dst + 144) = make_uint4(d1[0], d1[1], d1[2], d1[3]);
  }
  int cur = 0;
  for (int t = 0; t < 8; ++t) {
    const int k0 = t << 6;
    __syncthreads();
    if (t < 7) {
      #pragma unroll
      for (int it = 0; it < 2; ++it) {
        int q = qw + (it << 2);
        int c0 = k0 + 64 + (q << 3);
        const unsigned short* bp = (const unsigned short*)
            (fftf + (size_t)(b * MID + (c0 & 255)) * (2 * HW) + ((c0 < MID) ? HW : 0));
        const unsigned int* bp32 = (const unsigned int*)(bp + n0) + np;
        #pragma unroll
        for (int p = 0; p < 4; ++p) {
          ua[it][p] = bp32[(size_t)(2 * p) * (2 * HW)];
          ub[it][p] = bp32[(size_t)(2 * p + 1) * (2 * HW)];
        }
      }
    }
    #pragma unroll
    for (int kk = 0; kk < 2; ++kk) {
      short8 af[4], bf[4];
      #pragma unroll
      for (int mi = 0; mi < 4; ++mi)
        af[mi] = *(const short8*)&A[(size_t)(m0 + wm + (mi << 4) + l16) * (2 * MID)
                                    + k0 + (kk << 5) + (quad << 3)];
      #pragma unroll
      for (int ni = 0; ni < 4; ++ni) {
        int n = wn + (ni << 4) + l16;
        bf[ni] = *(const short8*)(Bs[cur] + n * 144 + ((((kk << 2) + quad) ^ ((n >> 1) & 7)) << 4));
      }
      #pragma unroll
      for (int mi = 0; mi < 4; ++mi)
        #pragma unroll
        for (int ni = 0; ni < 4; ++ni)
          acc[mi][ni] = __builtin_amdgcn_mfma_f32_16x16x32_bf16(af[mi], bf[ni], acc[mi][ni], 0, 0, 0);
    }
    if (t < 7) {
      #pragma unroll
      for (int it = 0; it < 2; ++it) {
        int q = qw + (it << 2);
        unsigned int d0[4], d1[4];
        #pragma unroll
        for (int p = 0; p < 4; ++p) {
          d0[p] = (ua[it][p] & 0xffffu) | (ub[it][p] << 16);
          d1[p] = (ua[it][p] >> 16) | (ub[it][p] & 0xffff0000u);
        }
        char* dst = Bs[cur ^ 1] + (np << 1) * 144 + ((q ^ (np & 7)) << 4);
        *(uint4*)dst = make_uint4(d0[0], d0[1], d0[2], d0[3]);
        *(uint4*)(dst + 144) = make_uint4(d1[0], d1[1], d1[2], d1[3]);
      }
    }
    cur ^= 1;
  }
  #pragma unroll
  for (int mi = 0; mi < 4; ++mi)
    #pragma unroll
    for (int reg = 0; reg < 4; ++reg) {
      int m = m0 + wm + (mi << 4) + (quad << 2) + reg;
      float bv = bias[m];
      size_t base = ((size_t)b * CIN + m) * HW + n0 + wn + l16;
      #pragma unroll
      for (int ni = 0; ni < 4; ++ni)
        y[base + (ni << 4)] = acc[mi][ni][reg] + bv + x[base + (ni << 4)];
    }
}

// ------------------------------------------------------------------ K2: depthwise 3x3 + BN + ReLU + spatial mean
__global__ __launch_bounds__(256) void k_dwbn(
    const float* __restrict__ in, const float* __restrict__ dww,
    const float* __restrict__ dwb, const float* __restrict__ gamma,
    const float* __restrict__ beta, const float* __restrict__ mean,
    const float* __restrict__ var, float* __restrict__ out,
    float* __restrict__ g0)
{
  __shared__ float pl[HW];
  __shared__ float red[256];
  const int p = blockIdx.x;
  const int c = p & (MID - 1);
  const int tid = threadIdx.x;
  const float* ip = in + (size_t)p * HW;
  for (int l = tid; l < HW; l += 256) pl[l] = ip[l];
  float wreg[9];
  #pragma unroll
  for (int i = 0; i < 9; ++i) wreg[i] = dww[c * 9 + i];
  const float bconv = dwb[c];
  const float inv = gamma[c] * rsqrtf(var[c] + 1e-5f);
  const float mu = mean[c], bt = beta[c];
  __syncthreads();
  float lsum = 0.f;
  float* op = out + (size_t)p * HW;
  for (int l = tid; l < HW; l += 256) {
    int y = l >> 6, xx0 = l & 63;
    float s = bconv;
    #pragma unroll
    for (int ky = 0; ky < 3; ++ky) {
      int yy = y + ky - 1;
      if (yy < 0 || yy >= 64) continue;
      #pragma unroll
      for (int kx = 0; kx < 3; ++kx) {
        int xx = xx0 + kx - 1;
        if (xx < 0 || xx >= 64) continue;
        s = fmaf(pl[(yy << 6) + xx], wreg[ky * 3 + kx], s);
      }
    }
    s = (s - mu) * inv + bt;
    s = fmaxf(s, 0.f);
    op[l] = s;
    lsum += s;
  }
  red[tid] = lsum;
  __syncthreads();
  for (int st = 128; st > 0; st >>= 1) {
    if (tid < st) red[tid] += red[tid + st];
    __syncthreads();
  }
  if (tid == 0) g0[p] = red[0] * (1.f / HW);
}

// ------------------------------------------------------------------ K3: SE gate MLP (tiny)
__global__ __launch_bounds__(256) void k_gate(
    const float* __restrict__ g0, const float* __restrict__ w1,
    const float* __restrict__ b1, const float* __restrict__ w2,
    const float* __restrict__ b2, float* __restrict__ g)
{
  __shared__ float gs[MID];
  __shared__ float hs[32];
  const int b = blockIdx.x;
  const int tid = threadIdx.x;
  gs[tid] = g0[b * MID + tid];
  __syncthreads();
  if (tid < 32) {
    float s = b1[tid];
    for (int c = 0; c < MID; ++c) s = fmaf(gs[c], w1[tid * MID + c], s);
    hs[tid] = fmaxf(s, 0.f);
  }
  __syncthreads();
  float s = b2[tid];
  #pragma unroll
  for (int j = 0; j < 32; ++j) s = fmaf(hs[j], w2[tid * 32 + j], s);
  g[b * MID + tid] = 1.f / (1.f + expf(-s));
}

// ------------------------------------------------------------------ K4: forward 2D DFT (ortho), real input -> complex out (+ plane norm^2)
__global__ __launch_bounds__(256) void k_fft_fwd(
    const float* __restrict__ in, float* __restrict__ outf,
    float* __restrict__ Nbuf)
{
  __shared__ float2 buf[64 * 64];
  __shared__ float2 tw[64];
  __shared__ float red[256];
  const int tid = threadIdx.x;
  const int p = blockIdx.x;
  if (tid < 64) {
    float ang = -PI2 * (float)tid * (1.f / 64.f);
    tw[tid] = make_float2(cosf(ang), sinf(ang));
  }
  const float* ip = in + (size_t)p * HW;
  for (int l = tid; l < HW; l += 256)
    buf[swidx(l >> 6, l & 63)] = make_float2(ip[l], 0.f);
  __syncthreads();
  dft64_pass<-1, 0>(buf, tw, tid);
  dft64_pass<-1, 1>(buf, tw, tid);
  float2* op = (float2*)(outf + (size_t)p * (2 * HW));
  float lsum = 0.f;
  for (int l = tid; l < HW; l += 256) {
    float2 v = buf[swidx(l >> 6, l & 63)];
    float vx = v.x * (1.f / 64.f), vy = v.y * (1.f / 64.f);
    op[l] = make_float2(vx, vy);
    lsum = fmaf(vx, vx, fmaf(vy, vy, lsum));
  }
  red[tid] = lsum;
  __syncthreads();
  for (int st = 128; st > 0; st >>= 1) {
    if (tid < st) red[tid] += red[tid + st];
    __syncthreads();
  }
  if (tid == 0) Nbuf[p] = red[0];
}

// ------------------------------------------------------------------ K5a: attention scores via MFMA Gram
__global__ __launch_bounds__(256) void k_attn_s(
    const float* __restrict__ fftf, float* __restrict__ Sbuf)
{
  __shared__ float red[4 * 1024];
  const int bh = blockIdx.y;
  const int ks = blockIdx.x;
  const int b = bh >> 3, h = bh & 7;
  const int tid = threadIdx.x;
  const int lane = tid & 63, wave = tid >> 6;
  const int r  = lane & 31;
  const int hi = lane >> 5;
  const float* rowp = fftf + (size_t)(b * MID + h * CH + r) * (2 * HW)
                    + (size_t)ks * (2 * HW / KSPL) + wave * (2 * HW / KSPL / 4)
                    + (hi << 3);
  floatx16 acc = {};
  #pragma unroll
  for (int st = 0; st < (2 * HW / KSPL / 4) / 16; ++st) {
    float4 f0 = *(const float4*)(rowp + st * 16);
    float4 f1 = *(const float4*)(rowp + st * 16 + 4);
    short8 a;
    a[0] = (short)f2b(f0.x); a[1] = (short)f2b(f0.y);
    a[2] = (short)f2b(f0.z); a[3] = (short)f2b(f0.w);
    a[4] = (short)f2b(f1.x); a[5] = (short)f2b(f1.y);
    a[6] = (short)f2b(f1.z); a[7] = (short)f2b(f1.w);
    uint4 av = *(uint4*)&a;
    uint4 bv = make_uint4(av.x ^ 0x80000000u, av.y ^ 0x80000000u,
                          av.z ^ 0x80000000u, av.w ^ 0x80000000u);
    short8 bn = *(short8*)&bv;
    acc = __builtin_amdgcn_mfma_f32_32x32x16_bf16(a, bn, acc, 0, 0, 0);
  }
  #pragma unroll
  for (int i = 0; i < 16; ++i) {
    const int row = (i & 3) + ((i >> 2) << 3) + (hi << 2);
    red[wave * 1024 + row * 32 + r] = acc[i];
  }
  __syncthreads();
  float* Sp = Sbuf + ((size_t)bh * KSPL + ks) * 1024;
  #pragma unroll
  for (int e = tid; e < 1024; e += 256)
    Sp[e] = red[e] + red[1024 + e] + red[2048 + e] + red[3072 + e];
}

// ------------------------------------------------------------------ K5b: sum partials + normalize + temperature + softmax -> Pbuf
__global__ __launch_bounds__(64) void k_attn_sm(
    const float* __restrict__ Sbuf, const float* __restrict__ Nbuf,
    const float* __restrict__ temp, float* __restrict__ Pbuf)
{
  const int bh = blockIdx.x;
  const int h = bh & 7;
  const int tid = threadIdx.x;
  if (tid < 32) {
    float nc = fmaxf(sqrtf(Nbuf[bh * 32 + tid]), 1e-12f);
    float tmp = temp[h];
    const float* Sp = Sbuf + (size_t)bh * (KSPL * 1024) + tid * 32;
    float vals[32];
    float vmax = -1e30f;
    #pragma unroll
    for (int d = 0; d < 32; ++d) {
      float s = 0.f;
      #pragma unroll
      for (int ksx = 0; ksx < KSPL; ++ksx) s += Sp[ksx * 1024 + d];
      float nd = fmaxf(sqrtf(Nbuf[bh * 32 + d]), 1e-12f);
      float v = s / (nc * nd) * tmp;
      vals[d] = v;
      vmax = fmaxf(vmax, v);
    }
    float sum = 0.f;
    #pragma unroll
    for (int d = 0; d < 32; ++d) {
      float e = expf(vals[d] - vmax);
      vals[d] = e;
      sum += e;
    }
    float rinv = 1.f / sum;
    float* Pp = Pbuf + (size_t)bh * 1024 + tid * 32;
    #pragma unroll
    for (int d = 0; d < 32; ++d) Pp[d] = vals[d] * rinv;
  }
}

// ------------------------------------------------------------------ K5c: out[c,n] = sum_d P[c,d] * Re(Q[d,n])
__global__ __launch_bounds__(256) void k_attn_o(
    const float* __restrict__ fftf, const float* __restrict__ Pbuf,
    float* __restrict__ outw)
{
  const int bh = blockIdx.y;
  const int n0 = blockIdx.x << 9;
  const int b = bh >> 3, h = bh & 7;
  const float2* Q = (const float2*)fftf + ((size_t)b * MID + (size_t)h * CH) * HW;
  __shared__ float P[1024];
  __shared__ float Lr[32 * 514];
  const int tid = threadIdx.x;
  for (int l = tid; l < 1024; l += 256) P[l] = Pbuf[(size_t)bh * 1024 + l];
  for (int l = tid; l < 32 * 512; l += 256) {
    int r = l >> 9, nn = l & 511;
    Lr[r * 514 + nn] = Q[(size_t)r * HW + n0 + nn].x;
  }
  __syncthreads();
  const float2* Lr2 = (const float2*)Lr;
  const float4* P4 = (const float4*)P;
  float* orow = outw + ((size_t)b * MID + (size_t)h * CH) * HW + n0;
  #pragma unroll 4
  for (int c = 0; c < 32; ++c) {
    float s0 = 0.f, s1 = 0.f;
    #pragma unroll
    for (int j = 0; j < 8; ++j) {
      float4 pv = P4[c * 8 + j];
      int d = j << 2;
      float2 v0 = Lr2[(d + 0) * 257 + tid];
      float2 v1 = Lr2[(d + 1) * 257 + tid];
      float2 v2 = Lr2[(d + 2) * 257 + tid];
      float2 v3 = Lr2[(d + 3) * 257 + tid];
      s0 = fmaf(pv.x, v0.x, s0); s1 = fmaf(pv.x, v0.y, s1);
      s0 = fmaf(pv.y, v1.x, s0); s1 = fmaf(pv.y, v1.y, s1);
      s0 = fmaf(pv.z, v2.x, s0); s1 = fmaf(pv.z, v2.y, s1);
      s0 = fmaf(pv.w, v3.x, s0); s1 = fmaf(pv.w, v3.y, s1);
    }
    ((float2*)(orow + (size_t)c * HW))[tid] = make_float2(s0, s1);
  }
}

// ------------------------------------------------------------------ K6: attn inverse transform -> bf16 into plane bytes [16KB,24KB)
__global__ __launch_bounds__(256) void k_ifft_re(
    const float* __restrict__ in, float* __restrict__ fftf)
{
  __shared__ float2 buf[64 * 64];
  __shared__ float2 tw[64];
  const int tid = threadIdx.x;
  const int p = blockIdx.x;
  if (tid < 64) {
    float ang = -PI2 * (float)tid * (1.f / 64.f);
    tw[tid] = make_float2(cosf(ang), sinf(ang));
  }
  const float* ip = in + (size_t)p * HW;
  for (int l = tid; l < HW; l += 256)
    buf[swidx(l >> 6, l & 63)] = make_float2(ip[l], 0.f);
  __syncthreads();
  dft64_pass<-1, 0>(buf, tw, tid);
  dft64_pass<-1, 1>(buf, tw, tid);
  unsigned short* op = (unsigned short*)(fftf + (size_t)p * (2 * HW) + HW);
  for (int l = tid; l < HW; l += 256) {
    float2 v = buf[swidx(l >> 6, l & 63)];
    op[l] = f2b(v.x * (1.f / 64.f));
  }
}

// ------------------------------------------------------------------ K7: fwm -> bf16 into plane bytes [0,8KB)
__global__ __launch_bounds__(256) void k_fwm(
    float* __restrict__ fftf, const float* __restrict__ g)
{
  __shared__ float2 buf[64 * 64];
  __shared__ float2 tw[64];
  const int tid = threadIdx.x;
  const int p = blockIdx.x;
  if (tid < 64) {
    float ang = PI2 * (float)tid * (1.f / 64.f);
    tw[tid] = make_float2(cosf(ang), sinf(ang));
  }
  float* plane = fftf + (size_t)p * (2 * HW);
  const float2* F = (const float2*)plane;
  for (int l = tid; l < HW; l += 256) {
    float2 v = F[l];
    buf[swidx(l >> 6, l & 63)] = make_float2(v.x * v.x - v.y * v.y, 2.f * v.x * v.y);
  }
  __syncthreads();
  dft64_pass<1, 0>(buf, tw, tid);
  dft64_pass<1, 1>(buf, tw, tid);
  const float gg = g[p] * (1.f / 64.f);
  unsigned short* ob = (unsigned short*)plane;
  for (int l = tid; l < HW; l += 256) {
    float2 v = buf[swidx(l >> 6, l & 63)];
    ob[l] = f2b(v.x * gg);
  }
}

// ------------------------------------------------------------------ launch
extern "C" void kernel_launch(void* const* d_in, const int* in_sizes, int n_in,
                              void* d_out, int out_size, void* d_ws, size_t ws_size,
                              hipStream_t stream)
{
  const float* x    = (const float*)d_in[0];
  const float* rw   = (const float*)d_in[1];
  const float* rb   = (const float*)d_in[2];
  const float* dww  = (const float*)d_in[3];
  const float* dwb  = (const float*)d_in[4];
  const float* bng  = (const float*)d_in[5];
  const float* bnb  = (const float*)d_in[6];
  const float* bnm  = (const float*)d_in[7];
  const float* bnv  = (const float*)d_in[8];
  const float* gw1  = (const float*)d_in[9];
  const float* gb1  = (const float*)d_in[10];
  const float* gw2  = (const float*)d_in[11];
  const float* gb2  = (const float*)d_in[12];
  const float* temp = (const float*)d_in[13];
  const float* pw   = (const float*)d_in[14];
  const float* pb   = (const float*)d_in[15];
  float* y = (float*)d_out;

  float* ws = (float*)d_ws;
  const size_t PL = (size_t)BATCH * MID * HW;
  float* xr   = ws;                       // dwbn out (fp32); dead after k_fft_fwd
  float* fftf = ws + PL;                  // complex planes; later bf16 fwm/osp
  float* g0   = ws + 3 * PL;
  float* gg   = g0 + BATCH * MID;
  float* Nbuf = gg + BATCH * MID;         // [BATCH*MID] plane norms (fp32)
  unsigned short* rwB = (unsigned short*)(Nbuf + BATCH * MID);
  unsigned short* pwB = rwB + MID * CIN;
  // Sbuf/Pbuf alias the dead xr region (k_attn_s runs after k_fft_fwd)
  float* Sbuf = xr;                                  // [128][KSPL][1024]
  float* Pbuf = xr + (size_t)BATCH * HEADS * KSPL * 1024;  // [128][1024]
  float* xr0  = y;                        // d_out as scratch: reduce out, then attn out

  k_castw    <<<dim3(1024),            256, 0, stream>>>(rw, pw, rwB, pwB);
  k_gemm_red <<<dim3(32, 2, BATCH),    256, 0, stream>>>(rwB, x, rb, xr0);
  k_dwbn     <<<dim3(BATCH * MID),     256, 0, stream>>>(xr0, dww, dwb, bng, bnb, bnm, bnv, xr, g0);
  k_gate     <<<dim3(BATCH),           256, 0, stream>>>(g0, gw1, gb1, gw2, gb2, gg);
  k_fft_fwd  <<<dim3(BATCH * MID),     256, 0, stream>>>(xr, fftf, Nbuf);
  k_attn_s   <<<dim3(KSPL, BATCH * HEADS), 256, 0, stream>>>(fftf, Sbuf);
  k_attn_sm  <<<dim3(BATCH * HEADS),   64,  0, stream>>>(Sbuf, Nbuf, temp, Pbuf);
  k_attn_o   <<<dim3(8, BATCH * HEADS), 256, 0, stream>>>(fftf, Pbuf, xr0);
  k_fwm      <<<dim3(BATCH * MID),     256, 0, stream>>>(fftf, gg);
  k_ifft_re  <<<dim3(BATCH * MID),     256, 0, stream>>>(xr0, fftf);
  k_gemm_post<<<dim3(32, 4, BATCH),    256, 0, stream>>>(pwB, fftf, pb, x, y);
}

// Round 8
// 653.911 us; speedup vs baseline: 1.1916x; 1.1916x over previous
//
#include <hip/hip_runtime.h>
#include <math.h>

#define BATCH 16
#define CIN   512
#define MID   256
#define HW    4096
#define HEADS 8
#define CH    32
#define KSPL  8
#define PI2   6.2831853071795864769f
#define RT2H  0.70710678118654752440f

typedef __attribute__((ext_vector_type(8))) short short8;
typedef __attribute__((ext_vector_type(4))) float floatx4;
typedef __attribute__((ext_vector_type(16))) float floatx16;

__device__ inline unsigned short f2b(float f) {
  union { float f; unsigned int u; } v; v.f = f;
  unsigned int u = v.u;
  unsigned int r = (u + 0x7fffu + ((u >> 16) & 1u)) >> 16;
  return (unsigned short)r;
}

// ------------------------------------------------------------------ DFT helpers
__device__ __forceinline__ int swidx(int r, int n) {
  return (r << 6) + (n ^ (r & 15));
}

__device__ __forceinline__ void cmadd(float2& a, const float2 x,
                                      const float wr, const float wi) {
  a.x = fmaf(x.x, wr, a.x); a.x = fmaf(-x.y, wi, a.x);
  a.y = fmaf(x.x, wi, a.y); a.y = fmaf(x.y, wr, a.y);
}

// In-place 64-point DFT along axis; Cooley-Tukey 8x8 (see prior rounds).
template<int SGN, int AXIS>
__device__ __forceinline__ void dft64_pass(float2* __restrict__ buf,
                                           const float2* __restrict__ tw,
                                           const int tid)
{
  constexpr float W8R[8] = {1.f, RT2H, 0.f, -RT2H, -1.f, -RT2H, 0.f, RT2H};
  constexpr float W8I[8] = {0.f, RT2H, 1.f, RT2H, 0.f, -RT2H, -1.f, -RT2H};
  const int line = tid & 63;
  const int wv = tid >> 6;
  float2 xa[2][8];

  #pragma unroll
  for (int t = 0; t < 2; ++t) {
    const int b = wv + (t << 2);
    #pragma unroll
    for (int a = 0; a < 8; ++a) {
      const int i = (a << 3) + b;
      xa[t][a] = buf[AXIS ? swidx(line, i) : swidx(i, line)];
    }
  }
  __syncthreads();
  #pragma unroll
  for (int t = 0; t < 2; ++t) {
    const int b = wv + (t << 2);
    #pragma unroll
    for (int d = 0; d < 8; ++d) {
      float2 y = make_float2(0.f, 0.f);
      #pragma unroll
      for (int a = 0; a < 8; ++a) {
        const int j = (a * d) & 7;
        cmadd(y, xa[t][a], W8R[j], (float)SGN * W8I[j]);
      }
      const float2 tb = tw[(b * d) & 63];
      float2 z;
      z.x = y.x * tb.x - y.y * tb.y;
      z.y = y.x * tb.y + y.y * tb.x;
      const int i = (b << 3) + d;
      buf[AXIS ? swidx(line, i) : swidx(i, line)] = z;
    }
  }
  __syncthreads();

  #pragma unroll
  for (int t = 0; t < 2; ++t) {
    const int d = wv + (t << 2);
    #pragma unroll
    for (int b = 0; b < 8; ++b) {
      const int i = (b << 3) + d;
      xa[t][b] = buf[AXIS ? swidx(line, i) : swidx(i, line)];
    }
  }
  __syncthreads();
  #pragma unroll
  for (int t = 0; t < 2; ++t) {
    const int d = wv + (t << 2);
    #pragma unroll
    for (int c = 0; c < 8; ++c) {
      float2 s = make_float2(0.f, 0.f);
      #pragma unroll
      for (int b = 0; b < 8; ++b) {
        const int j = (b * c) & 7;
        cmadd(s, xa[t][b], W8R[j], (float)SGN * W8I[j]);
      }
      const int i = (c << 3) + d;
      buf[AXIS ? swidx(line, i) : swidx(i, line)] = s;
    }
  }
  __syncthreads();
}

// ------------------------------------------------------------------ K0: cast weights to bf16
__global__ __launch_bounds__(256) void k_castw(
    const float* __restrict__ rw, const float* __restrict__ pw,
    unsigned short* __restrict__ rwB, unsigned short* __restrict__ pwB)
{
  int i = blockIdx.x * 256 + threadIdx.x;
  if (i < MID * CIN) rwB[i] = f2b(rw[i]);
  if (i < CIN * 2 * MID) pwB[i] = f2b(pw[i]);
}

// ------------------------------------------------------------------ MFMA GEMM: C[M x N] = A[M x K bf16] * B[K x N] (+bias)(+resid)
// tile 128x128, BK=64, 4 waves, 4x4 mfma_f32_16x16x32_bf16 per wave.
// BOTH A and B double-buffered in LDS (rows of 144 B). Pipeline invariant:
// the MFMA phase reads ONLY LDS (lgkmcnt waits); global loads for tile t+1
// are ISSUED before the MFMAs and CONSUMED (vmcnt drain) only afterwards,
// by the ds_writes into buf[cur^1]. ONE barrier per K-step (write buffer !=
// read buffer). B swizzle q' = q ^ ((n>>1)&7) on write AND read.

// variant 1: B = fp32 global (x), converted during staging
__global__ __launch_bounds__(256) void k_gemm_red(
    const unsigned short* __restrict__ A, const float* __restrict__ Bg0,
    const float* __restrict__ bias, float* __restrict__ out)
{
  __shared__ __align__(16) char As[2][128 * 144];
  __shared__ __align__(16) char Bs[2][128 * 144];
  const int tid = threadIdx.x;
  const int n0 = blockIdx.x << 7;
  const int m0 = blockIdx.y << 7;
  const int b  = blockIdx.z;
  const int lane = tid & 63, wave = tid >> 6;
  const int wm = (wave >> 1) << 6, wn = (wave & 1) << 6;
  const int l16 = lane & 15, quad = lane >> 4;
  const int np = tid & 63;          // n-pair
  const int qw = tid >> 6;          // k-quad base; q = qw + 4*it
  const int am = tid >> 3;          // A row handled (per it: +32 rows? no: l>>3)
  const float* Bg = Bg0 + (size_t)b * CIN * HW;
  floatx4 acc[4][4] = {};
  uint4 apre[4];
  float2 pva[2][4], pvb[2][4];
  (void)am;

  // prologue: load tile 0 into regs, then stage to buffer 0
  #pragma unroll
  for (int it = 0; it < 4; ++it) {
    int l = tid + (it << 8);
    int m = l >> 3, ko = (l & 7) << 3;
    apre[it] = *(const uint4*)&A[(size_t)(m0 + m) * CIN + ko];
  }
  #pragma unroll
  for (int it = 0; it < 2; ++it) {
    int q = qw + (it << 2);
    const float* r0 = Bg + (size_t)(q << 3) * HW + n0 + (np << 1);
    #pragma unroll
    for (int p = 0; p < 4; ++p) {
      pva[it][p] = *(const float2*)(r0 + (size_t)(2 * p) * HW);
      pvb[it][p] = *(const float2*)(r0 + (size_t)(2 * p + 1) * HW);
    }
  }
  #pragma unroll
  for (int it = 0; it < 4; ++it) {
    int l = tid + (it << 8);
    int m = l >> 3, ko = (l & 7) << 3;
    *(uint4*)(As[0] + m * 144 + (ko << 1)) = apre[it];
  }
  #pragma unroll
  for (int it = 0; it < 2; ++it) {
    int q = qw + (it << 2);
    unsigned int d0[4], d1[4];
    #pragma unroll
    for (int p = 0; p < 4; ++p) {
      d0[p] = (unsigned)f2b(pva[it][p].x) | ((unsigned)f2b(pvb[it][p].x) << 16);
      d1[p] = (unsigned)f2b(pva[it][p].y) | ((unsigned)f2b(pvb[it][p].y) << 16);
    }
    char* dst = Bs[0] + (np << 1) * 144 + ((q ^ (np & 7)) << 4);
    *(uint4*)dst = make_uint4(d0[0], d0[1], d0[2], d0[3]);
    *(uint4*)(dst + 144) = make_uint4(d1[0], d1[1], d1[2], d1[3]);
  }
  int cur = 0;
  for (int t = 0; t < 8; ++t) {
    const int k0 = t << 6;
    __syncthreads();
    if (t < 7) {  // ISSUE loads for t+1; stay in flight across the MFMAs
      #pragma unroll
      for (int it = 0; it < 4; ++it) {
        int l = tid + (it << 8);
        int m = l >> 3, ko = (l & 7) << 3;
        apre[it] = *(const uint4*)&A[(size_t)(m0 + m) * CIN + k0 + 64 + ko];
      }
      #pragma unroll
      for (int it = 0; it < 2; ++it) {
        int q = qw + (it << 2);
        const float* r0 = Bg + (size_t)(k0 + 64 + (q << 3)) * HW + n0 + (np << 1);
        #pragma unroll
        for (int p = 0; p < 4; ++p) {
          pva[it][p] = *(const float2*)(r0 + (size_t)(2 * p) * HW);
          pvb[it][p] = *(const float2*)(r0 + (size_t)(2 * p + 1) * HW);
        }
      }
    }
    #pragma unroll
    for (int kk = 0; kk < 2; ++kk) {
      short8 af[4], bf[4];
      #pragma unroll
      for (int mi = 0; mi < 4; ++mi)
        af[mi] = *(const short8*)(As[cur] + (wm + (mi << 4) + l16) * 144 + (kk << 6) + (quad << 4));
      #pragma unroll
      for (int ni = 0; ni < 4; ++ni) {
        int n = wn + (ni << 4) + l16;
        bf[ni] = *(const short8*)(Bs[cur] + n * 144 + ((((kk << 2) + quad) ^ ((n >> 1) & 7)) << 4));
      }
      #pragma unroll
      for (int mi = 0; mi < 4; ++mi)
        #pragma unroll
        for (int ni = 0; ni < 4; ++ni)
          acc[mi][ni] = __builtin_amdgcn_mfma_f32_16x16x32_bf16(af[mi], bf[ni], acc[mi][ni], 0, 0, 0);
    }
    if (t < 7) {  // CONSUME loads: write into the other buffer (no barrier)
      #pragma unroll
      for (int it = 0; it < 4; ++it) {
        int l = tid + (it << 8);
        int m = l >> 3, ko = (l & 7) << 3;
        *(uint4*)(As[cur ^ 1] + m * 144 + (ko << 1)) = apre[it];
      }
      #pragma unroll
      for (int it = 0; it < 2; ++it) {
        int q = qw + (it << 2);
        unsigned int d0[4], d1[4];
        #pragma unroll
        for (int p = 0; p < 4; ++p) {
          d0[p] = (unsigned)f2b(pva[it][p].x) | ((unsigned)f2b(pvb[it][p].x) << 16);
          d1[p] = (unsigned)f2b(pva[it][p].y) | ((unsigned)f2b(pvb[it][p].y) << 16);
        }
        char* dst = Bs[cur ^ 1] + (np << 1) * 144 + ((q ^ (np & 7)) << 4);
        *(uint4*)dst = make_uint4(d0[0], d0[1], d0[2], d0[3]);
        *(uint4*)(dst + 144) = make_uint4(d1[0], d1[1], d1[2], d1[3]);
      }
    }
    cur ^= 1;
  }
  #pragma unroll
  for (int mi = 0; mi < 4; ++mi)
    #pragma unroll
    for (int reg = 0; reg < 4; ++reg) {
      int m = m0 + wm + (mi << 4) + (quad << 2) + reg;
      float bv = bias[m];
      size_t base = ((size_t)b * MID + m) * HW + n0 + wn + l16;
      #pragma unroll
      for (int ni = 0; ni < 4; ++ni)
        out[base + (ni << 4)] = acc[mi][ni][reg] + bv;
    }
}

// variant 2: B = bf16 rows scattered in fftf planes; +bias +residual
__global__ __launch_bounds__(256) void k_gemm_post(
    const unsigned short* __restrict__ A, const float* __restrict__ fftf,
    const float* __restrict__ bias, const float* __restrict__ x,
    float* __restrict__ y)
{
  __shared__ __align__(16) char As[2][128 * 144];
  __shared__ __align__(16) char Bs[2][128 * 144];
  const int tid = threadIdx.x;
  const int n0 = blockIdx.x << 7;
  const int m0 = blockIdx.y << 7;
  const int b  = blockIdx.z;
  const int lane = tid & 63, wave = tid >> 6;
  const int wm = (wave >> 1) << 6, wn = (wave & 1) << 6;
  const int l16 = lane & 15, quad = lane >> 4;
  const int np = tid & 63;
  const int qw = tid >> 6;
  floatx4 acc[4][4] = {};
  uint4 apre[4];
  unsigned int ua[2][4], ub[2][4];

  // prologue: load tile 0, stage to buffer 0
  #pragma unroll
  for (int it = 0; it < 4; ++it) {
    int l = tid + (it << 8);
    int m = l >> 3, ko = (l & 7) << 3;
    apre[it] = *(const uint4*)&A[(size_t)(m0 + m) * (2 * MID) + ko];
  }
  #pragma unroll
  for (int it = 0; it < 2; ++it) {
    int q = qw + (it << 2);
    int c0 = q << 3;                 // 8 channels, never straddles MID
    const unsigned short* bp = (const unsigned short*)
        (fftf + (size_t)(b * MID + (c0 & 255)) * (2 * HW) + ((c0 < MID) ? HW : 0));
    const unsigned int* bp32 = (const unsigned int*)(bp + n0) + np;
    #pragma unroll
    for (int p = 0; p < 4; ++p) {
      ua[it][p] = bp32[(size_t)(2 * p) * (2 * HW)];
      ub[it][p] = bp32[(size_t)(2 * p + 1) * (2 * HW)];
    }
  }
  #pragma unroll
  for (int it = 0; it < 4; ++it) {
    int l = tid + (it << 8);
    int m = l >> 3, ko = (l & 7) << 3;
    *(uint4*)(As[0] + m * 144 + (ko << 1)) = apre[it];
  }
  #pragma unroll
  for (int it = 0; it < 2; ++it) {
    int q = qw + (it << 2);
    unsigned int d0[4], d1[4];
    #pragma unroll
    for (int p = 0; p < 4; ++p) {
      d0[p] = (ua[it][p] & 0xffffu) | (ub[it][p] << 16);
      d1[p] = (ua[it][p] >> 16) | (ub[it][p] & 0xffff0000u);
    }
    char* dst = Bs[0] + (np << 1) * 144 + ((q ^ (np & 7)) << 4);
    *(uint4*)dst = make_uint4(d0[0], d0[1], d0[2], d0[3]);
    *(uint4*)(dst + 144) = make_uint4(d1[0], d1[1], d1[2], d1[3]);
  }
  int cur = 0;
  for (int t = 0; t < 8; ++t) {
    const int k0 = t << 6;
    __syncthreads();
    if (t < 7) {
      #pragma unroll
      for (int it = 0; it < 4; ++it) {
        int l = tid + (it << 8);
        int m = l >> 3, ko = (l & 7) << 3;
        apre[it] = *(const uint4*)&A[(size_t)(m0 + m) * (2 * MID) + k0 + 64 + ko];
      }
      #pragma unroll
      for (int it = 0; it < 2; ++it) {
        int q = qw + (it << 2);
        int c0 = k0 + 64 + (q << 3);
        const unsigned short* bp = (const unsigned short*)
            (fftf + (size_t)(b * MID + (c0 & 255)) * (2 * HW) + ((c0 < MID) ? HW : 0));
        const unsigned int* bp32 = (const unsigned int*)(bp + n0) + np;
        #pragma unroll
        for (int p = 0; p < 4; ++p) {
          ua[it][p] = bp32[(size_t)(2 * p) * (2 * HW)];
          ub[it][p] = bp32[(size_t)(2 * p + 1) * (2 * HW)];
        }
      }
    }
    #pragma unroll
    for (int kk = 0; kk < 2; ++kk) {
      short8 af[4], bf[4];
      #pragma unroll
      for (int mi = 0; mi < 4; ++mi)
        af[mi] = *(const short8*)(As[cur] + (wm + (mi << 4) + l16) * 144 + (kk << 6) + (quad << 4));
      #pragma unroll
      for (int ni = 0; ni < 4; ++ni) {
        int n = wn + (ni << 4) + l16;
        bf[ni] = *(const short8*)(Bs[cur] + n * 144 + ((((kk << 2) + quad) ^ ((n >> 1) & 7)) << 4));
      }
      #pragma unroll
      for (int mi = 0; mi < 4; ++mi)
        #pragma unroll
        for (int ni = 0; ni < 4; ++ni)
          acc[mi][ni] = __builtin_amdgcn_mfma_f32_16x16x32_bf16(af[mi], bf[ni], acc[mi][ni], 0, 0, 0);
    }
    if (t < 7) {
      #pragma unroll
      for (int it = 0; it < 4; ++it) {
        int l = tid + (it << 8);
        int m = l >> 3, ko = (l & 7) << 3;
        *(uint4*)(As[cur ^ 1] + m * 144 + (ko << 1)) = apre[it];
      }
      #pragma unroll
      for (int it = 0; it < 2; ++it) {
        int q = qw + (it << 2);
        unsigned int d0[4], d1[4];
        #pragma unroll
        for (int p = 0; p < 4; ++p) {
          d0[p] = (ua[it][p] & 0xffffu) | (ub[it][p] << 16);
          d1[p] = (ua[it][p] >> 16) | (ub[it][p] & 0xffff0000u);
        }
        char* dst = Bs[cur ^ 1] + (np << 1) * 144 + ((q ^ (np & 7)) << 4);
        *(uint4*)dst = make_uint4(d0[0], d0[1], d0[2], d0[3]);
        *(uint4*)(dst + 144) = make_uint4(d1[0], d1[1], d1[2], d1[3]);
      }
    }
    cur ^= 1;
  }
  #pragma unroll
  for (int mi = 0; mi < 4; ++mi)
    #pragma unroll
    for (int reg = 0; reg < 4; ++reg) {
      int m = m0 + wm + (mi << 4) + (quad << 2) + reg;
      float bv = bias[m];
      size_t base = ((size_t)b * CIN + m) * HW + n0 + wn + l16;
      #pragma unroll
      for (int ni = 0; ni < 4; ++ni)
        y[base + (ni << 4)] = acc[mi][ni][reg] + bv + x[base + (ni << 4)];
    }
}

// ------------------------------------------------------------------ K2: depthwise 3x3 + BN + ReLU + spatial mean
__global__ __launch_bounds__(256) void k_dwbn(
    const float* __restrict__ in, const float* __restrict__ dww,
    const float* __restrict__ dwb, const float* __restrict__ gamma,
    const float* __restrict__ beta, const float* __restrict__ mean,
    const float* __restrict__ var, float* __restrict__ out,
    float* __restrict__ g0)
{
  __shared__ float pl[HW];
  __shared__ float red[256];
  const int p = blockIdx.x;
  const int c = p & (MID - 1);
  const int tid = threadIdx.x;
  const float* ip = in + (size_t)p * HW;
  for (int l = tid; l < HW; l += 256) pl[l] = ip[l];
  float wreg[9];
  #pragma unroll
  for (int i = 0; i < 9; ++i) wreg[i] = dww[c * 9 + i];
  const float bconv = dwb[c];
  const float inv = gamma[c] * rsqrtf(var[c] + 1e-5f);
  const float mu = mean[c], bt = beta[c];
  __syncthreads();
  float lsum = 0.f;
  float* op = out + (size_t)p * HW;
  for (int l = tid; l < HW; l += 256) {
    int y = l >> 6, xx0 = l & 63;
    float s = bconv;
    #pragma unroll
    for (int ky = 0; ky < 3; ++ky) {
      int yy = y + ky - 1;
      if (yy < 0 || yy >= 64) continue;
      #pragma unroll
      for (int kx = 0; kx < 3; ++kx) {
        int xx = xx0 + kx - 1;
        if (xx < 0 || xx >= 64) continue;
        s = fmaf(pl[(yy << 6) + xx], wreg[ky * 3 + kx], s);
      }
    }
    s = (s - mu) * inv + bt;
    s = fmaxf(s, 0.f);
    op[l] = s;
    lsum += s;
  }
  red[tid] = lsum;
  __syncthreads();
  for (int st = 128; st > 0; st >>= 1) {
    if (tid < st) red[tid] += red[tid + st];
    __syncthreads();
  }
  if (tid == 0) g0[p] = red[0] * (1.f / HW);
}

// ------------------------------------------------------------------ K3: SE gate MLP (tiny)
__global__ __launch_bounds__(256) void k_gate(
    const float* __restrict__ g0, const float* __restrict__ w1,
    const float* __restrict__ b1, const float* __restrict__ w2,
    const float* __restrict__ b2, float* __restrict__ g)
{
  __shared__ float gs[MID];
  __shared__ float hs[32];
  const int b = blockIdx.x;
  const int tid = threadIdx.x;
  gs[tid] = g0[b * MID + tid];
  __syncthreads();
  if (tid < 32) {
    float s = b1[tid];
    for (int c = 0; c < MID; ++c) s = fmaf(gs[c], w1[tid * MID + c], s);
    hs[tid] = fmaxf(s, 0.f);
  }
  __syncthreads();
  float s = b2[tid];
  #pragma unroll
  for (int j = 0; j < 32; ++j) s = fmaf(hs[j], w2[tid * 32 + j], s);
  g[b * MID + tid] = 1.f / (1.f + expf(-s));
}

// ------------------------------------------------------------------ K4: forward 2D DFT (ortho), real input -> complex out (+ plane norm^2)
__global__ __launch_bounds__(256) void k_fft_fwd(
    const float* __restrict__ in, float* __restrict__ outf,
    float* __restrict__ Nbuf)
{
  __shared__ float2 buf[64 * 64];
  __shared__ float2 tw[64];
  __shared__ float red[256];
  const int tid = threadIdx.x;
  const int p = blockIdx.x;
  if (tid < 64) {
    float ang = -PI2 * (float)tid * (1.f / 64.f);
    tw[tid] = make_float2(cosf(ang), sinf(ang));
  }
  const float* ip = in + (size_t)p * HW;
  for (int l = tid; l < HW; l += 256)
    buf[swidx(l >> 6, l & 63)] = make_float2(ip[l], 0.f);
  __syncthreads();
  dft64_pass<-1, 0>(buf, tw, tid);
  dft64_pass<-1, 1>(buf, tw, tid);
  float2* op = (float2*)(outf + (size_t)p * (2 * HW));
  float lsum = 0.f;
  for (int l = tid; l < HW; l += 256) {
    float2 v = buf[swidx(l >> 6, l & 63)];
    float vx = v.x * (1.f / 64.f), vy = v.y * (1.f / 64.f);
    op[l] = make_float2(vx, vy);
    lsum = fmaf(vx, vx, fmaf(vy, vy, lsum));
  }
  red[tid] = lsum;
  __syncthreads();
  for (int st = 128; st > 0; st >>= 1) {
    if (tid < st) red[tid] += red[tid + st];
    __syncthreads();
  }
  if (tid == 0) Nbuf[p] = red[0];
}

// ------------------------------------------------------------------ K5a: attention scores via MFMA Gram
__global__ __launch_bounds__(256) void k_attn_s(
    const float* __restrict__ fftf, float* __restrict__ Sbuf)
{
  __shared__ float red[4 * 1024];
  const int bh = blockIdx.y;
  const int ks = blockIdx.x;
  const int b = bh >> 3, h = bh & 7;
  const int tid = threadIdx.x;
  const int lane = tid & 63, wave = tid >> 6;
  const int r  = lane & 31;
  const int hi = lane >> 5;
  const float* rowp = fftf + (size_t)(b * MID + h * CH + r) * (2 * HW)
                    + (size_t)ks * (2 * HW / KSPL) + wave * (2 * HW / KSPL / 4)
                    + (hi << 3);
  floatx16 acc = {};
  #pragma unroll
  for (int st = 0; st < (2 * HW / KSPL / 4) / 16; ++st) {
    float4 f0 = *(const float4*)(rowp + st * 16);
    float4 f1 = *(const float4*)(rowp + st * 16 + 4);
    short8 a;
    a[0] = (short)f2b(f0.x); a[1] = (short)f2b(f0.y);
    a[2] = (short)f2b(f0.z); a[3] = (short)f2b(f0.w);
    a[4] = (short)f2b(f1.x); a[5] = (short)f2b(f1.y);
    a[6] = (short)f2b(f1.z); a[7] = (short)f2b(f1.w);
    uint4 av = *(uint4*)&a;
    uint4 bv = make_uint4(av.x ^ 0x80000000u, av.y ^ 0x80000000u,
                          av.z ^ 0x80000000u, av.w ^ 0x80000000u);
    short8 bn = *(short8*)&bv;
    acc = __builtin_amdgcn_mfma_f32_32x32x16_bf16(a, bn, acc, 0, 0, 0);
  }
  #pragma unroll
  for (int i = 0; i < 16; ++i) {
    const int row = (i & 3) + ((i >> 2) << 3) + (hi << 2);
    red[wave * 1024 + row * 32 + r] = acc[i];
  }
  __syncthreads();
  float* Sp = Sbuf + ((size_t)bh * KSPL + ks) * 1024;
  #pragma unroll
  for (int e = tid; e < 1024; e += 256)
    Sp[e] = red[e] + red[1024 + e] + red[2048 + e] + red[3072 + e];
}

// ------------------------------------------------------------------ K5b: sum partials + normalize + temperature + softmax -> Pbuf
__global__ __launch_bounds__(64) void k_attn_sm(
    const float* __restrict__ Sbuf, const float* __restrict__ Nbuf,
    const float* __restrict__ temp, float* __restrict__ Pbuf)
{
  const int bh = blockIdx.x;
  const int h = bh & 7;
  const int tid = threadIdx.x;
  if (tid < 32) {
    float nc = fmaxf(sqrtf(Nbuf[bh * 32 + tid]), 1e-12f);
    float tmp = temp[h];
    const float* Sp = Sbuf + (size_t)bh * (KSPL * 1024) + tid * 32;
    float vals[32];
    float vmax = -1e30f;
    #pragma unroll
    for (int d = 0; d < 32; ++d) {
      float s = 0.f;
      #pragma unroll
      for (int ksx = 0; ksx < KSPL; ++ksx) s += Sp[ksx * 1024 + d];
      float nd = fmaxf(sqrtf(Nbuf[bh * 32 + d]), 1e-12f);
      float v = s / (nc * nd) * tmp;
      vals[d] = v;
      vmax = fmaxf(vmax, v);
    }
    float sum = 0.f;
    #pragma unroll
    for (int d = 0; d < 32; ++d) {
      float e = expf(vals[d] - vmax);
      vals[d] = e;
      sum += e;
    }
    float rinv = 1.f / sum;
    float* Pp = Pbuf + (size_t)bh * 1024 + tid * 32;
    #pragma unroll
    for (int d = 0; d < 32; ++d) Pp[d] = vals[d] * rinv;
  }
}

// ------------------------------------------------------------------ K5c: out[c,n] = sum_d P[c,d] * Re(Q[d,n])
__global__ __launch_bounds__(256) void k_attn_o(
    const float* __restrict__ fftf, const float* __restrict__ Pbuf,
    float* __restrict__ outw)
{
  const int bh = blockIdx.y;
  const int n0 = blockIdx.x << 9;
  const int b = bh >> 3, h = bh & 7;
  const float2* Q = (const float2*)fftf + ((size_t)b * MID + (size_t)h * CH) * HW;
  __shared__ float P[1024];
  __shared__ float Lr[32 * 514];
  const int tid = threadIdx.x;
  for (int l = tid; l < 1024; l += 256) P[l] = Pbuf[(size_t)bh * 1024 + l];
  for (int l = tid; l < 32 * 512; l += 256) {
    int r = l >> 9, nn = l & 511;
    Lr[r * 514 + nn] = Q[(size_t)r * HW + n0 + nn].x;
  }
  __syncthreads();
  const float2* Lr2 = (const float2*)Lr;
  const float4* P4 = (const float4*)P;
  float* orow = outw + ((size_t)b * MID + (size_t)h * CH) * HW + n0;
  #pragma unroll 4
  for (int c = 0; c < 32; ++c) {
    float s0 = 0.f, s1 = 0.f;
    #pragma unroll
    for (int j = 0; j < 8; ++j) {
      float4 pv = P4[c * 8 + j];
      int d = j << 2;
      float2 v0 = Lr2[(d + 0) * 257 + tid];
      float2 v1 = Lr2[(d + 1) * 257 + tid];
      float2 v2 = Lr2[(d + 2) * 257 + tid];
      float2 v3 = Lr2[(d + 3) * 257 + tid];
      s0 = fmaf(pv.x, v0.x, s0); s1 = fmaf(pv.x, v0.y, s1);
      s0 = fmaf(pv.y, v1.x, s0); s1 = fmaf(pv.y, v1.y, s1);
      s0 = fmaf(pv.z, v2.x, s0); s1 = fmaf(pv.z, v2.y, s1);
      s0 = fmaf(pv.w, v3.x, s0); s1 = fmaf(pv.w, v3.y, s1);
    }
    ((float2*)(orow + (size_t)c * HW))[tid] = make_float2(s0, s1);
  }
}

// ------------------------------------------------------------------ K6: attn inverse transform -> bf16 into plane bytes [16KB,24KB)
__global__ __launch_bounds__(256) void k_ifft_re(
    const float* __restrict__ in, float* __restrict__ fftf)
{
  __shared__ float2 buf[64 * 64];
  __shared__ float2 tw[64];
  const int tid = threadIdx.x;
  const int p = blockIdx.x;
  if (tid < 64) {
    float ang = -PI2 * (float)tid * (1.f / 64.f);
    tw[tid] = make_float2(cosf(ang), sinf(ang));
  }
  const float* ip = in + (size_t)p * HW;
  for (int l = tid; l < HW; l += 256)
    buf[swidx(l >> 6, l & 63)] = make_float2(ip[l], 0.f);
  __syncthreads();
  dft64_pass<-1, 0>(buf, tw, tid);
  dft64_pass<-1, 1>(buf, tw, tid);
  unsigned short* op = (unsigned short*)(fftf + (size_t)p * (2 * HW) + HW);
  for (int l = tid; l < HW; l += 256) {
    float2 v = buf[swidx(l >> 6, l & 63)];
    op[l] = f2b(v.x * (1.f / 64.f));
  }
}

// ------------------------------------------------------------------ K7: fwm -> bf16 into plane bytes [0,8KB)
__global__ __launch_bounds__(256) void k_fwm(
    float* __restrict__ fftf, const float* __restrict__ g)
{
  __shared__ float2 buf[64 * 64];
  __shared__ float2 tw[64];
  const int tid = threadIdx.x;
  const int p = blockIdx.x;
  if (tid < 64) {
    float ang = PI2 * (float)tid * (1.f / 64.f);
    tw[tid] = make_float2(cosf(ang), sinf(ang));
  }
  float* plane = fftf + (size_t)p * (2 * HW);
  const float2* F = (const float2*)plane;
  for (int l = tid; l < HW; l += 256) {
    float2 v = F[l];
    buf[swidx(l >> 6, l & 63)] = make_float2(v.x * v.x - v.y * v.y, 2.f * v.x * v.y);
  }
  __syncthreads();
  dft64_pass<1, 0>(buf, tw, tid);
  dft64_pass<1, 1>(buf, tw, tid);
  const float gg = g[p] * (1.f / 64.f);
  unsigned short* ob = (unsigned short*)plane;
  for (int l = tid; l < HW; l += 256) {
    float2 v = buf[swidx(l >> 6, l & 63)];
    ob[l] = f2b(v.x * gg);
  }
}

// ------------------------------------------------------------------ launch
extern "C" void kernel_launch(void* const* d_in, const int* in_sizes, int n_in,
                              void* d_out, int out_size, void* d_ws, size_t ws_size,
                              hipStream_t stream)
{
  const float* x    = (const float*)d_in[0];
  const float* rw   = (const float*)d_in[1];
  const float* rb   = (const float*)d_in[2];
  const float* dww  = (const float*)d_in[3];
  const float* dwb  = (const float*)d_in[4];
  const float* bng  = (const float*)d_in[5];
  const float* bnb  = (const float*)d_in[6];
  const float* bnm  = (const float*)d_in[7];
  const float* bnv  = (const float*)d_in[8];
  const float* gw1  = (const float*)d_in[9];
  const float* gb1  = (const float*)d_in[10];
  const float* gw2  = (const float*)d_in[11];
  const float* gb2  = (const float*)d_in[12];
  const float* temp = (const float*)d_in[13];
  const float* pw   = (const float*)d_in[14];
  const float* pb   = (const float*)d_in[15];
  float* y = (float*)d_out;

  float* ws = (float*)d_ws;
  const size_t PL = (size_t)BATCH * MID * HW;
  float* xr   = ws;                       // dwbn out (fp32); dead after k_fft_fwd
  float* fftf = ws + PL;                  // complex planes; later bf16 fwm/osp
  float* g0   = ws + 3 * PL;
  float* gg   = g0 + BATCH * MID;
  float* Nbuf = gg + BATCH * MID;         // [BATCH*MID] plane norms (fp32)
  unsigned short* rwB = (unsigned short*)(Nbuf + BATCH * MID);
  unsigned short* pwB = rwB + MID * CIN;
  // Sbuf/Pbuf alias the dead xr region (k_attn_s runs after k_fft_fwd)
  float* Sbuf = xr;                                  // [128][KSPL][1024]
  float* Pbuf = xr + (size_t)BATCH * HEADS * KSPL * 1024;  // [128][1024]
  float* xr0  = y;                        // d_out as scratch: reduce out, then attn out

  k_castw    <<<dim3(1024),            256, 0, stream>>>(rw, pw, rwB, pwB);
  k_gemm_red <<<dim3(32, 2, BATCH),    256, 0, stream>>>(rwB, x, rb, xr0);
  k_dwbn     <<<dim3(BATCH * MID),     256, 0, stream>>>(xr0, dww, dwb, bng, bnb, bnm, bnv, xr, g0);
  k_gate     <<<dim3(BATCH),           256, 0, stream>>>(g0, gw1, gb1, gw2, gb2, gg);
  k_fft_fwd  <<<dim3(BATCH * MID),     256, 0, stream>>>(xr, fftf, Nbuf);
  k_attn_s   <<<dim3(KSPL, BATCH * HEADS), 256, 0, stream>>>(fftf, Sbuf);
  k_attn_sm  <<<dim3(BATCH * HEADS),   64,  0, stream>>>(Sbuf, Nbuf, temp, Pbuf);
  k_attn_o   <<<dim3(8, BATCH * HEADS), 256, 0, stream>>>(fftf, Pbuf, xr0);
  k_fwm      <<<dim3(BATCH * MID),     256, 0, stream>>>(fftf, gg);
  k_ifft_re  <<<dim3(BATCH * MID),     256, 0, stream>>>(xr0, fftf);
  k_gemm_post<<<dim3(32, 4, BATCH),    256, 0, stream>>>(pwB, fftf, pb, x, y);
}